// Round 17
// baseline (251.334 us; speedup 1.0000x reference)
//
#include <hip/hip_runtime.h>

#define NN 8192
#define UNITS 33
#define NCOLS 32
#define NSTEPS 512          // NN / 16
#define NCHUNKB 8           // block-level K chunks
#define CHUNKK (NN / NCHUNKB)   // 1024
#define TILEK 256
#define TPC (CHUNKK / TILEK)    // 4 tiles per chunk
#define NSLAB NCHUNKB           // 8 slabs (full per-block merge)

// ---- VALU fallback geometry (R10, proven) ----
#define RPB 16
#define KT 32
#define NT (NN / KT)
#define SA_STRIDE 20
#define SZ_STRIDE 36
#define SA_MAT (KT * SA_STRIDE)
#define SZ_SRC (KT * SZ_STRIDE)
#define SA_FLOATS (4 * SA_MAT)
#define SZ_BASE SA_FLOATS
#define SH_FLOATS (SA_FLOATS + 4 * SZ_SRC)

typedef __attribute__((ext_vector_type(2)))  float f32x2;
typedef __attribute__((ext_vector_type(4)))  float f32x4;
typedef __attribute__((ext_vector_type(16))) float f32x16;
typedef __attribute__((ext_vector_type(8)))  short bf16x8;
typedef __attribute__((ext_vector_type(4)))  unsigned int u32x4;

union FragU { u32x4 u; bf16x8 s; };

#define MFMA(a, b, c) __builtin_amdgcn_mfma_f32_32x32x16_bf16(a, b, c, 0, 0, 0)

__device__ __forceinline__ float bfr(float v) {
    unsigned int u = __builtin_bit_cast(unsigned int, v);
    u = (u + 0x7FFFu + ((u >> 16) & 1u)) & 0xFFFF0000u;
    return __builtin_bit_cast(float, u);
}

__device__ __forceinline__ void split1(float v, unsigned int &h, unsigned int &l) {
    unsigned int u = __builtin_bit_cast(unsigned int, v);
    unsigned int hu = u >> 16;
    float hf = __builtin_bit_cast(float, hu << 16);
    float r = v - hf;
    unsigned int ru = __builtin_bit_cast(unsigned int, r);
    h = hu;
    l = (ru + 0x8000u) >> 16;
}

__device__ __forceinline__ void packHL(const unsigned int* h, const unsigned int* l,
                                       bf16x8 &hi, bf16x8 &lo) {
    FragU H, L;
    H.u.x = h[0] | (h[1] << 16); H.u.y = h[2] | (h[3] << 16);
    H.u.z = h[4] | (h[5] << 16); H.u.w = h[6] | (h[7] << 16);
    L.u.x = l[0] | (l[1] << 16); L.u.y = l[2] | (l[3] << 16);
    L.u.z = l[4] | (l[5] << 16); L.u.w = l[6] | (l[7] << 16);
    hi = H.s; lo = L.s;
}

__device__ __forceinline__ void mk_split(f32x4 a0, f32x4 a1, bf16x8 &hi, bf16x8 &lo) {
    unsigned int h[8], l[8];
#pragma unroll
    for (int e = 0; e < 4; ++e) { split1(a0[e], h[e], l[e]); split1(a1[e], h[e + 4], l[e + 4]); }
    packHL(h, l, hi, lo);
}

__device__ __forceinline__ bf16x8 fneg(bf16x8 f) {
    FragU x; x.s = f;
    x.u.x ^= 0x80008000u; x.u.y ^= 0x80008000u; x.u.z ^= 0x80008000u; x.u.w ^= 0x80008000u;
    return x.s;
}

// Runtime C/D placement probe (any bijection): D[m][n] = 8*(m + 64n) exactly.
__device__ __forceinline__ void probe_cd(int lane, int pm[16], int pn[16]) {
    int m = lane & 31, half = lane >> 5;
    unsigned int am, dummy;
    split1((float)m, am, dummy);
    unsigned int a1; split1(1.0f, a1, dummy);
    unsigned int bn; split1((float)(64 * m), bn, dummy);
    unsigned int av = (half == 0) ? am : a1;
    unsigned int bv = (half == 0) ? a1 : bn;
    FragU A, B;
    A.u.x = A.u.y = A.u.z = A.u.w = av | (av << 16);
    B.u.x = B.u.y = B.u.z = B.u.w = bv | (bv << 16);
    f32x16 d = {};
    d = MFMA(A.s, B.s, d);
#pragma unroll
    for (int r = 0; r < 16; ++r) {
        unsigned int u = (unsigned int)(d[r] * 0.125f + 0.5f);
        pm[r] = (int)(u & 63u);
        pn[r] = (int)(u >> 6);
    }
}

__device__ __forceinline__ void ctanhd(float af, float bf, float &re, float &im) {
    double a = (double)af, b = (double)bf;
    double e  = exp(2.0 * a);
    double ei = 1.0 / e;
    double ch = 0.5 * (e + ei);
    double sh = 0.5 * (e - ei);
    double cb = cos(2.0 * b);
    double sb = sin(2.0 * b);
    double d  = ch + cb;
    re = (float)(sh / d);
    im = (float)(sb / d);
}

__global__ void __launch_bounds__(256) hopf_zero(float* __restrict__ out, int n) {
    int i = blockIdx.x * 256 + threadIdx.x;
    if (i < n) out[i] = 0.0f;
}

// ---------------------------------------------------------------------------
// Kernel 1: pack skinny operands into hi/lo B-fragments (4 MiB, L2-resident).
// ---------------------------------------------------------------------------
__global__ void __launch_bounds__(256) hopf_prep(
    const float* __restrict__ xre, const float* __restrict__ xim,
    const float* __restrict__ zre, const float* __restrict__ zim,
    u32x4* __restrict__ bfrag) {
    int idx  = blockIdx.x * 256 + threadIdx.x;
    int lane = idx & 63;
    int src  = (idx >> 6) & 3;      // 0=zr 1=zi 2=xr 3=xi
    int step = idx >> 8;            // 0..511
    int n    = lane & 31;
    int half = lane >> 5;

    const float* base;
    int stride, coloff;
    if      (src == 0) { base = zre; stride = UNITS; coloff = 1; }
    else if (src == 1) { base = zim; stride = UNITS; coloff = 1; }
    else if (src == 2) { base = xre; stride = NCOLS; coloff = 0; }
    else               { base = xim; stride = NCOLS; coloff = 0; }

    unsigned int h[8], l[8];
#pragma unroll
    for (int e = 0; e < 8; ++e) {
        int k = step * 16 + 8 * half + e;
        split1(base[(size_t)k * stride + coloff + n], h[e], l[e]);
    }
    bf16x8 hi, lo;
    packHL(h, l, hi, lo);
    FragU H; H.s = hi;
    FragU L; L.s = lo;
    size_t o = (size_t)step * 512 + (size_t)src * 128 + lane;
    bfrag[o]      = H.u;
    bfrag[o + 64] = L.u;
}

// ---------------------------------------------------------------------------
// 3-term split-bf16 compute for one K=16 step (proven math).
// ---------------------------------------------------------------------------
struct AStep {
    f32x4 ar0, ar1, ai0, ai1, br0, br1, bi0, bi1;
};

__device__ __forceinline__ void computeStep(const AStep& s, const u32x4* __restrict__ pb,
                                            f32x16& arc, f32x16& aic) {
    FragU zrh, zrl, zih, zil, xrh, xrl, xih, xil;
    zrh.u = pb[0];   zrl.u = pb[64];
    zih.u = pb[128]; zil.u = pb[192];
    xrh.u = pb[256]; xrl.u = pb[320];
    xih.u = pb[384]; xil.u = pb[448];

    bf16x8 arh, arl, aih, ail, brh, brl, bih, bil;
    mk_split(s.ar0, s.ar1, arh, arl);
    mk_split(s.ai0, s.ai1, aih, ail);
    mk_split(s.br0, s.br1, brh, brl);
    mk_split(s.bi0, s.bi1, bih, bil);
    bf16x8 nih = fneg(aih), nil = fneg(ail);
    bf16x8 nbh = fneg(bih), nbl = fneg(bil);

    arc = MFMA(arh, zrh.s, arc); arc = MFMA(arh, zrl.s, arc); arc = MFMA(arl, zrh.s, arc);
    arc = MFMA(nih, zih.s, arc); arc = MFMA(nih, zil.s, arc); arc = MFMA(nil, zih.s, arc);
    arc = MFMA(brh, xrh.s, arc); arc = MFMA(brh, xrl.s, arc); arc = MFMA(brl, xrh.s, arc);
    arc = MFMA(nbh, xih.s, arc); arc = MFMA(nbh, xil.s, arc); arc = MFMA(nbl, xih.s, arc);
    aic = MFMA(arh, zih.s, aic); aic = MFMA(arh, zil.s, aic); aic = MFMA(arl, zih.s, aic);
    aic = MFMA(aih, zrh.s, aic); aic = MFMA(aih, zrl.s, aic); aic = MFMA(ail, zrh.s, aic);
    aic = MFMA(brh, xih.s, aic); aic = MFMA(brh, xil.s, aic); aic = MFMA(brl, xih.s, aic);
    aic = MFMA(bih, xrh.s, aic); aic = MFMA(bih, xrl.s, aic); aic = MFMA(bil, xrh.s, aic);
}

// ---------------------------------------------------------------------------
// Kernel 2: LDS-staged MFMA GEMM, 8-wave blocks, TILEK=256 -> each staging
// instruction reads ONE ROW's full 1KB tile-span (64 lanes x 16B contiguous)
// = 2x larger DRAM granule than R16. LDS 128 KiB (1 block/CU). Wave w stages
// rows (w&1)*16..+15 of matrix w>>1 (16 x 1KB loads), computes K-steps
// s = 2w, 2w+1 per tile. Full 3-level LDS merge -> 1 slab per block
// (8 slabs total, 16 MB), no atomics.
// ---------------------------------------------------------------------------
__global__ void __launch_bounds__(512) hopf_mfma2(
    const float* __restrict__ Are, const float* __restrict__ Aim,
    const float* __restrict__ Bre, const float* __restrict__ Bim,
    const u32x4* __restrict__ bfrag, float* __restrict__ partial,
    unsigned long long ws_floats) {
    __shared__ float SH[4 * 8192];   // 128 KiB: [mat][kgran 0..63][rowperm 0..31][4]
    const int tid  = threadIdx.x;
    const int lane = tid & 63;
    const int w    = tid >> 6;          // wave 0..7
    const int r    = lane & 31;         // output row within tile (compute)
    const int half = lane >> 5;
    const int chunk  = blockIdx.x & 7;          // 0..7
    const int rowgrp = blockIdx.x >> 3;         // 0..255
    const int m0 = rowgrp * 32;
    const size_t k0chunk = (size_t)chunk * CHUNKK;

    const int mat = w >> 1;             // matrix this wave stages
    const int rh  = w & 1;              // row half (0: rows 0-15, 1: rows 16-31)
    const float* matp = (mat == 0) ? Are : (mat == 1) ? Aim : (mat == 2) ? Bre : Bim;

    f32x16 arc = {};
    f32x16 aic = {};
    f32x4 st[16];

    // prologue: load tile 0 (16 loads; each instr = one row x 1KB contiguous)
#pragma unroll
    for (int i = 0; i < 16; ++i)
        st[i] = *(const f32x4*)(matp + (size_t)(m0 + rh * 16 + i) * NN
                                + k0chunk + lane * 4);

    for (int t = 0; t < TPC; ++t) {
        __syncthreads();   // previous tile's LDS reads complete
        // stage tile t: b128 writes, XOR-permuted rows. granule g = lane.
#pragma unroll
        for (int i = 0; i < 16; ++i) {
            int row = rh * 16 + i;
            int rp  = (row ^ (lane & 31)) & 31;
            *(f32x4*)&SH[mat * 8192 + lane * 128 + rp * 4] = st[i];
        }
        __syncthreads();

        // prefetch tile t+1 into regs (overlaps with compute below)
        if (t + 1 < TPC) {
#pragma unroll
            for (int i = 0; i < 16; ++i)
                st[i] = *(const f32x4*)(matp + (size_t)(m0 + rh * 16 + i) * NN
                                        + k0chunk + (size_t)(t + 1) * TILEK + lane * 4);
        }

        // compute: wave w does K-steps s = 2w, 2w+1 of this tile (16 steps)
#pragma unroll
        for (int tt = 0; tt < 2; ++tt) {
            const int s = 2 * w + tt;
            const int kg0 = s * 4 + 2 * half;
            const int kg1 = kg0 + 1;
            const int rp0 = ((r ^ (kg0 & 31)) & 31) * 4;
            const int rp1 = ((r ^ (kg1 & 31)) & 31) * 4;
            AStep a;
            a.ar0 = *(const f32x4*)&SH[0 * 8192 + kg0 * 128 + rp0];
            a.ar1 = *(const f32x4*)&SH[0 * 8192 + kg1 * 128 + rp1];
            a.ai0 = *(const f32x4*)&SH[1 * 8192 + kg0 * 128 + rp0];
            a.ai1 = *(const f32x4*)&SH[1 * 8192 + kg1 * 128 + rp1];
            a.br0 = *(const f32x4*)&SH[2 * 8192 + kg0 * 128 + rp0];
            a.br1 = *(const f32x4*)&SH[2 * 8192 + kg1 * 128 + rp1];
            a.bi0 = *(const f32x4*)&SH[3 * 8192 + kg0 * 128 + rp0];
            a.bi1 = *(const f32x4*)&SH[3 * 8192 + kg1 * 128 + rp1];
            const int gstep = chunk * (CHUNKK / 16) + t * 16 + s;
            const u32x4* pb = bfrag + (size_t)gstep * 512 + lane;
            computeStep(a, pb, arc, aic);
        }
    }

    // epilogue: full 3-level merge of 8 waves through LDS -> wave 0 writes
    // slab `chunk`. All barriers uniform across the block.
    __syncthreads();
    if (w >= 4) {
        float* dst = &SH[(w - 4) * 2112 + lane * 33];
#pragma unroll
        for (int rr = 0; rr < 16; ++rr) { dst[rr] = arc[rr]; dst[16 + rr] = aic[rr]; }
    }
    __syncthreads();
    if (w < 4) {
        const float* src = &SH[w * 2112 + lane * 33];
#pragma unroll
        for (int rr = 0; rr < 16; ++rr) { arc[rr] += src[rr]; aic[rr] += src[16 + rr]; }
    }
    __syncthreads();
    if (w == 2 || w == 3) {
        float* dst = &SH[(w - 2) * 2112 + lane * 33];
#pragma unroll
        for (int rr = 0; rr < 16; ++rr) { dst[rr] = arc[rr]; dst[16 + rr] = aic[rr]; }
    }
    __syncthreads();
    if (w < 2) {
        const float* src = &SH[w * 2112 + lane * 33];
#pragma unroll
        for (int rr = 0; rr < 16; ++rr) { arc[rr] += src[rr]; aic[rr] += src[16 + rr]; }
    }
    __syncthreads();
    if (w == 1) {
        float* dst = &SH[lane * 33];
#pragma unroll
        for (int rr = 0; rr < 16; ++rr) { dst[rr] = arc[rr]; dst[16 + rr] = aic[rr]; }
    }
    __syncthreads();
    if (w == 0) {
        const float* src = &SH[lane * 33];
#pragma unroll
        for (int rr = 0; rr < 16; ++rr) { arc[rr] += src[rr]; aic[rr] += src[16 + rr]; }

        int pm[16], pn[16];
        probe_cd(lane, pm, pn);
#pragma unroll
        for (int rr = 0; rr < 16; ++rr) {
            int mrow = m0 + pm[rr];
            size_t o = (size_t)chunk * (NN * NCOLS * 2) + ((size_t)mrow * NCOLS + pn[rr]) * 2;
            if (o + 2 <= ws_floats) {
                f32x2 v; v.x = arc[rr]; v.y = aic[rr];
                *(f32x2*)(partial + o) = v;
            }
        }
    }
}

// ---------------------------------------------------------------------------
// Kernel 3: reduce nchunk slabs, complex tanh, z0, REAL-part output.
// ---------------------------------------------------------------------------
__global__ void __launch_bounds__(256) hopf_finalize(
    const float* __restrict__ partial,
    const float* __restrict__ zre, const float* __restrict__ zim,
    float* __restrict__ out, int out_size, int nchunk) {
    int idx = blockIdx.x * 256 + threadIdx.x;
    if (idx >= NN * UNITS) return;
    int i = idx / UNITS, j = idx % UNITS;
    const bool interleaved = (out_size >= NN * UNITS * 2);
    float re, im;
    if (j == 0) {
        re = bfr(zre[(size_t)i * UNITS]);
        im = bfr(zim[(size_t)i * UNITS]);
    } else {
        size_t base = ((size_t)i * NCOLS + (j - 1)) * 2;
        float a = 0.0f, b = 0.0f;
#pragma unroll 4
        for (int c = 0; c < nchunk; ++c) {
            f32x2 v = *(const f32x2*)(partial + (size_t)c * (NN * NCOLS * 2) + base);
            a += v.x; b += v.y;
        }
        ctanhd(a, b, re, im);
        re = bfr(re); im = bfr(im);
    }
    if (interleaved) {
        if (2 * idx + 1 < out_size) { out[2 * idx] = re; out[2 * idx + 1] = im; }
    } else {
        if (idx < out_size) out[idx] = re;
    }
}

// ---------------------------------------------------------------------------
// Fallback: R10's passing pure-f32 VALU kernel, verbatim.
// ---------------------------------------------------------------------------
__global__ void __launch_bounds__(256) hopf_valu(
    const float* __restrict__ xre, const float* __restrict__ xim,
    const float* __restrict__ zre, const float* __restrict__ zim,
    const float* __restrict__ Are, const float* __restrict__ Aim,
    const float* __restrict__ Bre, const float* __restrict__ Bim,
    float* __restrict__ out, int out_size) {
    __shared__ float SH[SH_FLOATS];
    const int tid  = threadIdx.x;
    const int lane = tid & 63;
    const int wv   = tid >> 6;
    const int mh   = lane & 3;
    const int jh   = (lane >> 2) & 3;
    const int ks   = lane >> 4;
    const int m0   = blockIdx.x * RPB;
    const int sa_a  = tid >> 6;
    const int sa_r  = (tid >> 2) & 15;
    const int sa_kc = (tid & 3) * 8;

    float accr[4][8], acci[4][8];
#pragma unroll
    for (int dm = 0; dm < 4; ++dm)
#pragma unroll
        for (int dj = 0; dj < 8; ++dj) { accr[dm][dj] = 0.0f; acci[dm][dj] = 0.0f; }

    for (int kt = 0; kt < NT; ++kt) {
        const int k0 = kt * KT;
        __syncthreads();
        {
            const float* srcA = (sa_a == 0) ? Are : (sa_a == 1) ? Aim
                              : (sa_a == 2) ? Bre : Bim;
            const float* p = srcA + (size_t)(m0 + sa_r) * NN + k0 + sa_kc;
            f32x4 v0 = *(const f32x4*)(p);
            f32x4 v1 = *(const f32x4*)(p + 4);
#pragma unroll
            for (int i = 0; i < 4; ++i)
                SH[sa_a * SA_MAT + (sa_kc + i) * SA_STRIDE + sa_r] = v0[i];
#pragma unroll
            for (int i = 0; i < 4; ++i)
                SH[sa_a * SA_MAT + (sa_kc + 4 + i) * SA_STRIDE + sa_r] = v1[i];
        }
#pragma unroll
        for (int c = 0; c < 16; ++c) {
            const int s = c >> 2;
            const int k = (c & 3) * 8 + (tid >> 5);
            const int j = tid & 31;
            float v;
            if      (s == 0) v = zre[(size_t)(k0 + k) * UNITS + 1 + j];
            else if (s == 1) v = zim[(size_t)(k0 + k) * UNITS + 1 + j];
            else if (s == 2) v = xre[(size_t)(k0 + k) * 32 + j];
            else             v = xim[(size_t)(k0 + k) * 32 + j];
            SH[SZ_BASE + s * SZ_SRC + k * SZ_STRIDE + j] = v;
        }
        __syncthreads();

#pragma unroll
        for (int t = 0; t < 2; ++t) {
            const int kl = wv * 8 + ks * 2 + t;
            const float* sa = SH + kl * SA_STRIDE + mh * 4;
            f32x4 ar = *(const f32x4*)(sa + 0 * SA_MAT);
            f32x4 ai = *(const f32x4*)(sa + 1 * SA_MAT);
            f32x4 br = *(const f32x4*)(sa + 2 * SA_MAT);
            f32x4 bi = *(const f32x4*)(sa + 3 * SA_MAT);
            const float* sz = SH + SZ_BASE + kl * SZ_STRIDE + jh * 8;
            f32x4 zr0 = *(const f32x4*)(sz + 0 * SZ_SRC);
            f32x4 zr1 = *(const f32x4*)(sz + 0 * SZ_SRC + 4);
            f32x4 zi0 = *(const f32x4*)(sz + 1 * SZ_SRC);
            f32x4 zi1 = *(const f32x4*)(sz + 1 * SZ_SRC + 4);
            f32x4 xr0 = *(const f32x4*)(sz + 2 * SZ_SRC);
            f32x4 xr1 = *(const f32x4*)(sz + 2 * SZ_SRC + 4);
            f32x4 xi0 = *(const f32x4*)(sz + 3 * SZ_SRC);
            f32x4 xi1 = *(const f32x4*)(sz + 3 * SZ_SRC + 4);
#pragma unroll
            for (int dj = 0; dj < 8; ++dj) {
                const float vzr = (dj < 4) ? zr0[dj & 3] : zr1[dj & 3];
                const float vzi = (dj < 4) ? zi0[dj & 3] : zi1[dj & 3];
                const float vxr = (dj < 4) ? xr0[dj & 3] : xr1[dj & 3];
                const float vxi = (dj < 4) ? xi0[dj & 3] : xi1[dj & 3];
#pragma unroll
                for (int dm = 0; dm < 4; ++dm) {
                    float r = accr[dm][dj], q = acci[dm][dj];
                    r = fmaf(ar[dm],  vzr, r);
                    r = fmaf(-ai[dm], vzi, r);
                    r = fmaf(br[dm],  vxr, r);
                    r = fmaf(-bi[dm], vxi, r);
                    q = fmaf(ar[dm],  vzi, q);
                    q = fmaf(ai[dm],  vzr, q);
                    q = fmaf(br[dm],  vxi, q);
                    q = fmaf(bi[dm],  vxr, q);
                    accr[dm][dj] = r; acci[dm][dj] = q;
                }
            }
        }
    }

    __syncthreads();
    for (int i = tid; i < RPB * 32 * 2; i += 256) SH[i] = 0.0f;
    __syncthreads();
    const int myslot = wv * 4 + ks;
    for (int slot = 0; slot < 16; ++slot) {
        if (myslot == slot) {
#pragma unroll
            for (int dm = 0; dm < 4; ++dm)
#pragma unroll
                for (int dj = 0; dj < 8; ++dj) {
                    const int cell = (mh * 4 + dm) * 32 + (jh * 8 + dj);
                    SH[cell * 2 + 0] += accr[dm][dj];
                    SH[cell * 2 + 1] += acci[dm][dj];
                }
        }
        __syncthreads();
    }

    const bool interleaved = (out_size >= NN * UNITS * 2);
    {
        const int m = tid >> 4;
        const int j0 = tid & 15;
#pragma unroll
        for (int p = 0; p < 2; ++p) {
            const int j = j0 + p * 16;
            const float sr = SH[(m * 32 + j) * 2 + 0];
            const float si = SH[(m * 32 + j) * 2 + 1];
            float re, im;
            ctanhd(sr, si, re, im);
            const int e = (m0 + m) * UNITS + 1 + j;
            if (interleaved) {
                if (2 * e + 1 < out_size) { out[2 * e] = bfr(re); out[2 * e + 1] = bfr(im); }
            } else {
                if (e < out_size) out[e] = bfr(re);
            }
        }
        if (tid < RPB) {
            const int i = m0 + tid;
            const int e = i * UNITS;
            const float zr = bfr(zre[(size_t)i * UNITS]);
            const float zi = bfr(zim[(size_t)i * UNITS]);
            if (interleaved) {
                if (2 * e + 1 < out_size) { out[2 * e] = zr; out[2 * e + 1] = zi; }
            } else {
                if (e < out_size) out[e] = zr;
            }
        }
    }
}

extern "C" void kernel_launch(void* const* d_in, const int* in_sizes, int n_in,
                              void* d_out, int out_size, void* d_ws, size_t ws_size,
                              hipStream_t stream) {
    const int SX = NN * (UNITS - 1);
    const int SZn = NN * UNITS;
    const int SM = NN * NN;
    const float* xs[2] = {nullptr, nullptr};
    const float* zs[2] = {nullptr, nullptr};
    const float* ms[4] = {nullptr, nullptr, nullptr, nullptr};
    int nx = 0, nz = 0, nm = 0;
    for (int i = 0; i < n_in; ++i) {
        const float* p = (const float*)d_in[i];
        if      (in_sizes[i] == SX)  { if (nx < 2) xs[nx] = p; ++nx; }
        else if (in_sizes[i] == SZn) { if (nz < 2) zs[nz] = p; ++nz; }
        else if (in_sizes[i] == SM)  { if (nm < 4) ms[nm] = p; ++nm; }
    }
    float* out = (float*)d_out;

    if (nx != 2 || nz != 2 || nm != 4) {
        hopf_zero<<<(out_size + 255) / 256, 256, 0, stream>>>(out, out_size);
        return;
    }

    const float* xre = xs[0]; const float* xim = xs[1];
    const float* zre = zs[0]; const float* zim = zs[1];
    const float* Are = ms[0]; const float* Aim = ms[1];
    const float* Bre = ms[2]; const float* Bim = ms[3];

    const size_t SLAB_FLOATS = (size_t)NN * NCOLS * 2;                 // 524288
    const size_t SLAB_BYTES  = SLAB_FLOATS * 4;                        // 2 MiB
    const size_t BFRAG_BYTES = (size_t)NSTEPS * 512 * sizeof(u32x4);   // 4 MiB

    if (ws_size >= NSLAB * SLAB_BYTES + BFRAG_BYTES) {   // 20 MiB
        float* partial = (float*)d_ws;
        u32x4* bfrag   = (u32x4*)((char*)d_ws + NSLAB * SLAB_BYTES);
        unsigned long long wsf = (unsigned long long)(NSLAB * SLAB_FLOATS);
        hopf_prep<<<512, 256, 0, stream>>>(xre, xim, zre, zim, bfrag);
        hopf_mfma2<<<NCHUNKB * 256, 512, 0, stream>>>(Are, Aim, Bre, Bim, bfrag, partial, wsf);
        hopf_finalize<<<(NN * UNITS + 255) / 256, 256, 0, stream>>>(partial, zre, zim, out, out_size, NSLAB);
    } else {
        hopf_valu<<<NN / RPB, 256, 0, stream>>>(xre, xim, zre, zim,
                                                Are, Aim, Bre, Bim, out, out_size);
    }
}

// Round 18
// 212.117 us; speedup vs baseline: 1.1849x; 1.1849x over previous
//
#include <hip/hip_runtime.h>

#define NN 8192
#define UNITS 33
#define NCOLS 32
#define NSTEPS 512          // NN / 16
#define NCHUNKB 8           // block-level K chunks
#define CHUNKK (NN / NCHUNKB)   // 1024
#define TILEK 128
#define TPC (CHUNKK / TILEK)    // 8 tiles per chunk
#define NSLAB NCHUNKB           // 8 slabs (full per-block merge)

// ---- VALU fallback geometry (R10, proven) ----
#define RPB 16
#define KT 32
#define NT (NN / KT)
#define SA_STRIDE 20
#define SZ_STRIDE 36
#define SA_MAT (KT * SA_STRIDE)
#define SZ_SRC (KT * SZ_STRIDE)
#define SA_FLOATS (4 * SA_MAT)
#define SZ_BASE SA_FLOATS
#define SH_FLOATS (SA_FLOATS + 4 * SZ_SRC)

typedef __attribute__((ext_vector_type(2)))  float f32x2;
typedef __attribute__((ext_vector_type(4)))  float f32x4;
typedef __attribute__((ext_vector_type(16))) float f32x16;
typedef __attribute__((ext_vector_type(8)))  short bf16x8;
typedef __attribute__((ext_vector_type(4)))  unsigned int u32x4;

union FragU { u32x4 u; bf16x8 s; };

#define MFMA(a, b, c) __builtin_amdgcn_mfma_f32_32x32x16_bf16(a, b, c, 0, 0, 0)

__device__ __forceinline__ float bfr(float v) {
    unsigned int u = __builtin_bit_cast(unsigned int, v);
    u = (u + 0x7FFFu + ((u >> 16) & 1u)) & 0xFFFF0000u;
    return __builtin_bit_cast(float, u);
}

__device__ __forceinline__ void split1(float v, unsigned int &h, unsigned int &l) {
    unsigned int u = __builtin_bit_cast(unsigned int, v);
    unsigned int hu = u >> 16;
    float hf = __builtin_bit_cast(float, hu << 16);
    float r = v - hf;
    unsigned int ru = __builtin_bit_cast(unsigned int, r);
    h = hu;
    l = (ru + 0x8000u) >> 16;
}

__device__ __forceinline__ void packHL(const unsigned int* h, const unsigned int* l,
                                       bf16x8 &hi, bf16x8 &lo) {
    FragU H, L;
    H.u.x = h[0] | (h[1] << 16); H.u.y = h[2] | (h[3] << 16);
    H.u.z = h[4] | (h[5] << 16); H.u.w = h[6] | (h[7] << 16);
    L.u.x = l[0] | (l[1] << 16); L.u.y = l[2] | (l[3] << 16);
    L.u.z = l[4] | (l[5] << 16); L.u.w = l[6] | (l[7] << 16);
    hi = H.s; lo = L.s;
}

__device__ __forceinline__ void mk_split(f32x4 a0, f32x4 a1, bf16x8 &hi, bf16x8 &lo) {
    unsigned int h[8], l[8];
#pragma unroll
    for (int e = 0; e < 4; ++e) { split1(a0[e], h[e], l[e]); split1(a1[e], h[e + 4], l[e + 4]); }
    packHL(h, l, hi, lo);
}

__device__ __forceinline__ bf16x8 fneg(bf16x8 f) {
    FragU x; x.s = f;
    x.u.x ^= 0x80008000u; x.u.y ^= 0x80008000u; x.u.z ^= 0x80008000u; x.u.w ^= 0x80008000u;
    return x.s;
}

// Runtime C/D placement probe (any bijection): D[m][n] = 8*(m + 64n) exactly.
__device__ __forceinline__ void probe_cd(int lane, int pm[16], int pn[16]) {
    int m = lane & 31, half = lane >> 5;
    unsigned int am, dummy;
    split1((float)m, am, dummy);
    unsigned int a1; split1(1.0f, a1, dummy);
    unsigned int bn; split1((float)(64 * m), bn, dummy);
    unsigned int av = (half == 0) ? am : a1;
    unsigned int bv = (half == 0) ? a1 : bn;
    FragU A, B;
    A.u.x = A.u.y = A.u.z = A.u.w = av | (av << 16);
    B.u.x = B.u.y = B.u.z = B.u.w = bv | (bv << 16);
    f32x16 d = {};
    d = MFMA(A.s, B.s, d);
#pragma unroll
    for (int r = 0; r < 16; ++r) {
        unsigned int u = (unsigned int)(d[r] * 0.125f + 0.5f);
        pm[r] = (int)(u & 63u);
        pn[r] = (int)(u >> 6);
    }
}

__device__ __forceinline__ void ctanhd(float af, float bf, float &re, float &im) {
    double a = (double)af, b = (double)bf;
    double e  = exp(2.0 * a);
    double ei = 1.0 / e;
    double ch = 0.5 * (e + ei);
    double sh = 0.5 * (e - ei);
    double cb = cos(2.0 * b);
    double sb = sin(2.0 * b);
    double d  = ch + cb;
    re = (float)(sh / d);
    im = (float)(sb / d);
}

__global__ void __launch_bounds__(256) hopf_zero(float* __restrict__ out, int n) {
    int i = blockIdx.x * 256 + threadIdx.x;
    if (i < n) out[i] = 0.0f;
}

// ---------------------------------------------------------------------------
// Kernel 1: pack skinny operands into hi/lo B-fragments (4 MiB, L2-resident).
// ---------------------------------------------------------------------------
__global__ void __launch_bounds__(256) hopf_prep(
    const float* __restrict__ xre, const float* __restrict__ xim,
    const float* __restrict__ zre, const float* __restrict__ zim,
    u32x4* __restrict__ bfrag) {
    int idx  = blockIdx.x * 256 + threadIdx.x;
    int lane = idx & 63;
    int src  = (idx >> 6) & 3;      // 0=zr 1=zi 2=xr 3=xi
    int step = idx >> 8;            // 0..511
    int n    = lane & 31;
    int half = lane >> 5;

    const float* base;
    int stride, coloff;
    if      (src == 0) { base = zre; stride = UNITS; coloff = 1; }
    else if (src == 1) { base = zim; stride = UNITS; coloff = 1; }
    else if (src == 2) { base = xre; stride = NCOLS; coloff = 0; }
    else               { base = xim; stride = NCOLS; coloff = 0; }

    unsigned int h[8], l[8];
#pragma unroll
    for (int e = 0; e < 8; ++e) {
        int k = step * 16 + 8 * half + e;
        split1(base[(size_t)k * stride + coloff + n], h[e], l[e]);
    }
    bf16x8 hi, lo;
    packHL(h, l, hi, lo);
    FragU H; H.s = hi;
    FragU L; L.s = lo;
    size_t o = (size_t)step * 512 + (size_t)src * 128 + lane;
    bfrag[o]      = H.u;
    bfrag[o + 64] = L.u;
}

// ---------------------------------------------------------------------------
// 3-term split-bf16 compute for one K=16 step (proven math).
// ---------------------------------------------------------------------------
struct AStep {
    f32x4 ar0, ar1, ai0, ai1, br0, br1, bi0, bi1;
};

__device__ __forceinline__ void computeStep(const AStep& s, const u32x4* __restrict__ pb,
                                            f32x16& arc, f32x16& aic) {
    FragU zrh, zrl, zih, zil, xrh, xrl, xih, xil;
    zrh.u = pb[0];   zrl.u = pb[64];
    zih.u = pb[128]; zil.u = pb[192];
    xrh.u = pb[256]; xrl.u = pb[320];
    xih.u = pb[384]; xil.u = pb[448];

    bf16x8 arh, arl, aih, ail, brh, brl, bih, bil;
    mk_split(s.ar0, s.ar1, arh, arl);
    mk_split(s.ai0, s.ai1, aih, ail);
    mk_split(s.br0, s.br1, brh, brl);
    mk_split(s.bi0, s.bi1, bih, bil);
    bf16x8 nih = fneg(aih), nil = fneg(ail);
    bf16x8 nbh = fneg(bih), nbl = fneg(bil);

    arc = MFMA(arh, zrh.s, arc); arc = MFMA(arh, zrl.s, arc); arc = MFMA(arl, zrh.s, arc);
    arc = MFMA(nih, zih.s, arc); arc = MFMA(nih, zil.s, arc); arc = MFMA(nil, zih.s, arc);
    arc = MFMA(brh, xrh.s, arc); arc = MFMA(brh, xrl.s, arc); arc = MFMA(brl, xrh.s, arc);
    arc = MFMA(nbh, xih.s, arc); arc = MFMA(nbh, xil.s, arc); arc = MFMA(nbl, xih.s, arc);
    aic = MFMA(arh, zih.s, aic); aic = MFMA(arh, zil.s, aic); aic = MFMA(arl, zih.s, aic);
    aic = MFMA(aih, zrh.s, aic); aic = MFMA(aih, zrl.s, aic); aic = MFMA(ail, zrh.s, aic);
    aic = MFMA(brh, xih.s, aic); aic = MFMA(brh, xil.s, aic); aic = MFMA(brl, xih.s, aic);
    aic = MFMA(bih, xrh.s, aic); aic = MFMA(bih, xrl.s, aic); aic = MFMA(bil, xrh.s, aic);
}

// ---------------------------------------------------------------------------
// Kernel 2: R16's best config (TILEK=128, 8-wave blocks, 64 KiB LDS, 2
// blocks/CU = 16 waves/CU) + R17's full 3-level merge -> 1 slab per block
// (8 slabs total), no atomics.
// ---------------------------------------------------------------------------
__global__ void __launch_bounds__(512, 4) hopf_mfma2(
    const float* __restrict__ Are, const float* __restrict__ Aim,
    const float* __restrict__ Bre, const float* __restrict__ Bim,
    const u32x4* __restrict__ bfrag, float* __restrict__ partial,
    unsigned long long ws_floats) {
    __shared__ float SH[4 * 4096];   // 64 KiB: [mat][kgran 0..31][rowperm 0..31][4]
    const int tid  = threadIdx.x;
    const int lane = tid & 63;
    const int w    = tid >> 6;          // wave 0..7
    const int r    = lane & 31;         // output row within tile (compute)
    const int half = lane >> 5;
    const int chunk  = blockIdx.x & 7;          // 0..7 (== XCD under round-robin)
    const int rowgrp = blockIdx.x >> 3;         // 0..255
    const int m0 = rowgrp * 32;
    const size_t k0chunk = (size_t)chunk * CHUNKK;

    const int mat = w >> 1;             // matrix this wave stages
    const int rh  = w & 1;              // row half (0: rows 0-15, 1: rows 16-31)
    const float* matp = (mat == 0) ? Are : (mat == 1) ? Aim : (mat == 2) ? Bre : Bim;
    const int srh = lane >> 5;          // staging row parity 0..1
    const int skg = lane & 31;          // staging k-granule (16B) 0..31

    f32x16 arc = {};
    f32x16 aic = {};
    f32x4 st[8];

    // prologue: load tile 0 (8 loads; each instr = 2 rows x 512B contiguous)
#pragma unroll
    for (int i = 0; i < 8; ++i)
        st[i] = *(const f32x4*)(matp + (size_t)(m0 + rh * 16 + 2 * i + srh) * NN
                                + k0chunk + skg * 4);

    for (int t = 0; t < TPC; ++t) {
        __syncthreads();   // previous tile's LDS reads complete
        // stage tile t: b128 writes, XOR-permuted rows
#pragma unroll
        for (int i = 0; i < 8; ++i) {
            int row = rh * 16 + 2 * i + srh;
            int rp  = (row ^ skg) & 31;
            *(f32x4*)&SH[mat * 4096 + skg * 128 + rp * 4] = st[i];
        }
        __syncthreads();

        // prefetch tile t+1 into regs (overlaps with compute below)
        if (t + 1 < TPC) {
#pragma unroll
            for (int i = 0; i < 8; ++i)
                st[i] = *(const f32x4*)(matp + (size_t)(m0 + rh * 16 + 2 * i + srh) * NN
                                        + k0chunk + (size_t)(t + 1) * TILEK + skg * 4);
        }

        // compute: wave w does K-step s = w of this tile (8 steps, 8 waves)
        {
            const int kg0 = w * 4 + 2 * half;
            const int kg1 = kg0 + 1;
            AStep a;
            a.ar0 = *(const f32x4*)&SH[0 * 4096 + kg0 * 128 + ((r ^ kg0) & 31) * 4];
            a.ar1 = *(const f32x4*)&SH[0 * 4096 + kg1 * 128 + ((r ^ kg1) & 31) * 4];
            a.ai0 = *(const f32x4*)&SH[1 * 4096 + kg0 * 128 + ((r ^ kg0) & 31) * 4];
            a.ai1 = *(const f32x4*)&SH[1 * 4096 + kg1 * 128 + ((r ^ kg1) & 31) * 4];
            a.br0 = *(const f32x4*)&SH[2 * 4096 + kg0 * 128 + ((r ^ kg0) & 31) * 4];
            a.br1 = *(const f32x4*)&SH[2 * 4096 + kg1 * 128 + ((r ^ kg1) & 31) * 4];
            a.bi0 = *(const f32x4*)&SH[3 * 4096 + kg0 * 128 + ((r ^ kg0) & 31) * 4];
            a.bi1 = *(const f32x4*)&SH[3 * 4096 + kg1 * 128 + ((r ^ kg1) & 31) * 4];
            const int gstep = chunk * (CHUNKK / 16) + t * 8 + w;
            const u32x4* pb = bfrag + (size_t)gstep * 512 + lane;
            computeStep(a, pb, arc, aic);
        }
    }

    // epilogue: full 3-level merge of 8 waves through LDS (stride-33 padded)
    // -> wave 0 writes slab `chunk`. 8 slabs total. Barriers block-uniform.
    __syncthreads();
    if (w >= 4) {
        float* dst = &SH[(w - 4) * 2112 + lane * 33];
#pragma unroll
        for (int rr = 0; rr < 16; ++rr) { dst[rr] = arc[rr]; dst[16 + rr] = aic[rr]; }
    }
    __syncthreads();
    if (w < 4) {
        const float* src = &SH[w * 2112 + lane * 33];
#pragma unroll
        for (int rr = 0; rr < 16; ++rr) { arc[rr] += src[rr]; aic[rr] += src[16 + rr]; }
    }
    __syncthreads();
    if (w == 2 || w == 3) {
        float* dst = &SH[(w - 2) * 2112 + lane * 33];
#pragma unroll
        for (int rr = 0; rr < 16; ++rr) { dst[rr] = arc[rr]; dst[16 + rr] = aic[rr]; }
    }
    __syncthreads();
    if (w < 2) {
        const float* src = &SH[w * 2112 + lane * 33];
#pragma unroll
        for (int rr = 0; rr < 16; ++rr) { arc[rr] += src[rr]; aic[rr] += src[16 + rr]; }
    }
    __syncthreads();
    if (w == 1) {
        float* dst = &SH[lane * 33];
#pragma unroll
        for (int rr = 0; rr < 16; ++rr) { dst[rr] = arc[rr]; dst[16 + rr] = aic[rr]; }
    }
    __syncthreads();
    if (w == 0) {
        const float* src = &SH[lane * 33];
#pragma unroll
        for (int rr = 0; rr < 16; ++rr) { arc[rr] += src[rr]; aic[rr] += src[16 + rr]; }

        int pm[16], pn[16];
        probe_cd(lane, pm, pn);
#pragma unroll
        for (int rr = 0; rr < 16; ++rr) {
            int mrow = m0 + pm[rr];
            size_t o = (size_t)chunk * (NN * NCOLS * 2) + ((size_t)mrow * NCOLS + pn[rr]) * 2;
            if (o + 2 <= ws_floats) {
                f32x2 v; v.x = arc[rr]; v.y = aic[rr];
                *(f32x2*)(partial + o) = v;
            }
        }
    }
}

// ---------------------------------------------------------------------------
// Kernel 3: reduce nchunk slabs, complex tanh, z0, REAL-part output.
// ---------------------------------------------------------------------------
__global__ void __launch_bounds__(256) hopf_finalize(
    const float* __restrict__ partial,
    const float* __restrict__ zre, const float* __restrict__ zim,
    float* __restrict__ out, int out_size, int nchunk) {
    int idx = blockIdx.x * 256 + threadIdx.x;
    if (idx >= NN * UNITS) return;
    int i = idx / UNITS, j = idx % UNITS;
    const bool interleaved = (out_size >= NN * UNITS * 2);
    float re, im;
    if (j == 0) {
        re = bfr(zre[(size_t)i * UNITS]);
        im = bfr(zim[(size_t)i * UNITS]);
    } else {
        size_t base = ((size_t)i * NCOLS + (j - 1)) * 2;
        float a = 0.0f, b = 0.0f;
#pragma unroll 4
        for (int c = 0; c < nchunk; ++c) {
            f32x2 v = *(const f32x2*)(partial + (size_t)c * (NN * NCOLS * 2) + base);
            a += v.x; b += v.y;
        }
        ctanhd(a, b, re, im);
        re = bfr(re); im = bfr(im);
    }
    if (interleaved) {
        if (2 * idx + 1 < out_size) { out[2 * idx] = re; out[2 * idx + 1] = im; }
    } else {
        if (idx < out_size) out[idx] = re;
    }
}

// ---------------------------------------------------------------------------
// Fallback: R10's passing pure-f32 VALU kernel, verbatim.
// ---------------------------------------------------------------------------
__global__ void __launch_bounds__(256) hopf_valu(
    const float* __restrict__ xre, const float* __restrict__ xim,
    const float* __restrict__ zre, const float* __restrict__ zim,
    const float* __restrict__ Are, const float* __restrict__ Aim,
    const float* __restrict__ Bre, const float* __restrict__ Bim,
    float* __restrict__ out, int out_size) {
    __shared__ float SH[SH_FLOATS];
    const int tid  = threadIdx.x;
    const int lane = tid & 63;
    const int wv   = tid >> 6;
    const int mh   = lane & 3;
    const int jh   = (lane >> 2) & 3;
    const int ks   = lane >> 4;
    const int m0   = blockIdx.x * RPB;
    const int sa_a  = tid >> 6;
    const int sa_r  = (tid >> 2) & 15;
    const int sa_kc = (tid & 3) * 8;

    float accr[4][8], acci[4][8];
#pragma unroll
    for (int dm = 0; dm < 4; ++dm)
#pragma unroll
        for (int dj = 0; dj < 8; ++dj) { accr[dm][dj] = 0.0f; acci[dm][dj] = 0.0f; }

    for (int kt = 0; kt < NT; ++kt) {
        const int k0 = kt * KT;
        __syncthreads();
        {
            const float* srcA = (sa_a == 0) ? Are : (sa_a == 1) ? Aim
                              : (sa_a == 2) ? Bre : Bim;
            const float* p = srcA + (size_t)(m0 + sa_r) * NN + k0 + sa_kc;
            f32x4 v0 = *(const f32x4*)(p);
            f32x4 v1 = *(const f32x4*)(p + 4);
#pragma unroll
            for (int i = 0; i < 4; ++i)
                SH[sa_a * SA_MAT + (sa_kc + i) * SA_STRIDE + sa_r] = v0[i];
#pragma unroll
            for (int i = 0; i < 4; ++i)
                SH[sa_a * SA_MAT + (sa_kc + 4 + i) * SA_STRIDE + sa_r] = v1[i];
        }
#pragma unroll
        for (int c = 0; c < 16; ++c) {
            const int s = c >> 2;
            const int k = (c & 3) * 8 + (tid >> 5);
            const int j = tid & 31;
            float v;
            if      (s == 0) v = zre[(size_t)(k0 + k) * UNITS + 1 + j];
            else if (s == 1) v = zim[(size_t)(k0 + k) * UNITS + 1 + j];
            else if (s == 2) v = xre[(size_t)(k0 + k) * 32 + j];
            else             v = xim[(size_t)(k0 + k) * 32 + j];
            SH[SZ_BASE + s * SZ_SRC + k * SZ_STRIDE + j] = v;
        }
        __syncthreads();

#pragma unroll
        for (int t = 0; t < 2; ++t) {
            const int kl = wv * 8 + ks * 2 + t;
            const float* sa = SH + kl * SA_STRIDE + mh * 4;
            f32x4 ar = *(const f32x4*)(sa + 0 * SA_MAT);
            f32x4 ai = *(const f32x4*)(sa + 1 * SA_MAT);
            f32x4 br = *(const f32x4*)(sa + 2 * SA_MAT);
            f32x4 bi = *(const f32x4*)(sa + 3 * SA_MAT);
            const float* sz = SH + SZ_BASE + kl * SZ_STRIDE + jh * 8;
            f32x4 zr0 = *(const f32x4*)(sz + 0 * SZ_SRC);
            f32x4 zr1 = *(const f32x4*)(sz + 0 * SZ_SRC + 4);
            f32x4 zi0 = *(const f32x4*)(sz + 1 * SZ_SRC);
            f32x4 zi1 = *(const f32x4*)(sz + 1 * SZ_SRC + 4);
            f32x4 xr0 = *(const f32x4*)(sz + 2 * SZ_SRC);
            f32x4 xr1 = *(const f32x4*)(sz + 2 * SZ_SRC + 4);
            f32x4 xi0 = *(const f32x4*)(sz + 3 * SZ_SRC);
            f32x4 xi1 = *(const f32x4*)(sz + 3 * SZ_SRC + 4);
#pragma unroll
            for (int dj = 0; dj < 8; ++dj) {
                const float vzr = (dj < 4) ? zr0[dj & 3] : zr1[dj & 3];
                const float vzi = (dj < 4) ? zi0[dj & 3] : zi1[dj & 3];
                const float vxr = (dj < 4) ? xr0[dj & 3] : xr1[dj & 3];
                const float vxi = (dj < 4) ? xi0[dj & 3] : xi1[dj & 3];
#pragma unroll
                for (int dm = 0; dm < 4; ++dm) {
                    float r = accr[dm][dj], q = acci[dm][dj];
                    r = fmaf(ar[dm],  vzr, r);
                    r = fmaf(-ai[dm], vzi, r);
                    r = fmaf(br[dm],  vxr, r);
                    r = fmaf(-bi[dm], vxi, r);
                    q = fmaf(ar[dm],  vzi, q);
                    q = fmaf(ai[dm],  vzr, q);
                    q = fmaf(br[dm],  vxi, q);
                    q = fmaf(bi[dm],  vxr, q);
                    accr[dm][dj] = r; acci[dm][dj] = q;
                }
            }
        }
    }

    __syncthreads();
    for (int i = tid; i < RPB * 32 * 2; i += 256) SH[i] = 0.0f;
    __syncthreads();
    const int myslot = wv * 4 + ks;
    for (int slot = 0; slot < 16; ++slot) {
        if (myslot == slot) {
#pragma unroll
            for (int dm = 0; dm < 4; ++dm)
#pragma unroll
                for (int dj = 0; dj < 8; ++dj) {
                    const int cell = (mh * 4 + dm) * 32 + (jh * 8 + dj);
                    SH[cell * 2 + 0] += accr[dm][dj];
                    SH[cell * 2 + 1] += acci[dm][dj];
                }
        }
        __syncthreads();
    }

    const bool interleaved = (out_size >= NN * UNITS * 2);
    {
        const int m = tid >> 4;
        const int j0 = tid & 15;
#pragma unroll
        for (int p = 0; p < 2; ++p) {
            const int j = j0 + p * 16;
            const float sr = SH[(m * 32 + j) * 2 + 0];
            const float si = SH[(m * 32 + j) * 2 + 1];
            float re, im;
            ctanhd(sr, si, re, im);
            const int e = (m0 + m) * UNITS + 1 + j;
            if (interleaved) {
                if (2 * e + 1 < out_size) { out[2 * e] = bfr(re); out[2 * e + 1] = bfr(im); }
            } else {
                if (e < out_size) out[e] = bfr(re);
            }
        }
        if (tid < RPB) {
            const int i = m0 + tid;
            const int e = i * UNITS;
            const float zr = bfr(zre[(size_t)i * UNITS]);
            const float zi = bfr(zim[(size_t)i * UNITS]);
            if (interleaved) {
                if (2 * e + 1 < out_size) { out[2 * e] = zr; out[2 * e + 1] = zi; }
            } else {
                if (e < out_size) out[e] = zr;
            }
        }
    }
}

extern "C" void kernel_launch(void* const* d_in, const int* in_sizes, int n_in,
                              void* d_out, int out_size, void* d_ws, size_t ws_size,
                              hipStream_t stream) {
    const int SX = NN * (UNITS - 1);
    const int SZn = NN * UNITS;
    const int SM = NN * NN;
    const float* xs[2] = {nullptr, nullptr};
    const float* zs[2] = {nullptr, nullptr};
    const float* ms[4] = {nullptr, nullptr, nullptr, nullptr};
    int nx = 0, nz = 0, nm = 0;
    for (int i = 0; i < n_in; ++i) {
        const float* p = (const float*)d_in[i];
        if      (in_sizes[i] == SX)  { if (nx < 2) xs[nx] = p; ++nx; }
        else if (in_sizes[i] == SZn) { if (nz < 2) zs[nz] = p; ++nz; }
        else if (in_sizes[i] == SM)  { if (nm < 4) ms[nm] = p; ++nm; }
    }
    float* out = (float*)d_out;

    if (nx != 2 || nz != 2 || nm != 4) {
        hopf_zero<<<(out_size + 255) / 256, 256, 0, stream>>>(out, out_size);
        return;
    }

    const float* xre = xs[0]; const float* xim = xs[1];
    const float* zre = zs[0]; const float* zim = zs[1];
    const float* Are = ms[0]; const float* Aim = ms[1];
    const float* Bre = ms[2]; const float* Bim = ms[3];

    const size_t SLAB_FLOATS = (size_t)NN * NCOLS * 2;                 // 524288
    const size_t SLAB_BYTES  = SLAB_FLOATS * 4;                        // 2 MiB
    const size_t BFRAG_BYTES = (size_t)NSTEPS * 512 * sizeof(u32x4);   // 4 MiB

    if (ws_size >= NSLAB * SLAB_BYTES + BFRAG_BYTES) {   // 20 MiB
        float* partial = (float*)d_ws;
        u32x4* bfrag   = (u32x4*)((char*)d_ws + NSLAB * SLAB_BYTES);
        unsigned long long wsf = (unsigned long long)(NSLAB * SLAB_FLOATS);
        hopf_prep<<<512, 256, 0, stream>>>(xre, xim, zre, zim, bfrag);
        hopf_mfma2<<<NCHUNKB * 256, 512, 0, stream>>>(Are, Aim, Bre, Bim, bfrag, partial, wsf);
        hopf_finalize<<<(NN * UNITS + 255) / 256, 256, 0, stream>>>(partial, zre, zim, out, out_size, NSLAB);
    } else {
        hopf_valu<<<NN / RPB, 256, 0, stream>>>(xre, xim, zre, zim,
                                                Are, Aim, Bre, Bim, out, out_size);
    }
}